// Round 1
// baseline (1378.080 us; speedup 1.0000x reference)
//
#include <hip/hip_runtime.h>
#include <hip/hip_cooperative_groups.h>
#include <stdint.h>

namespace cg = cooperative_groups;

#define NROWS 32768
#define DDIM  512
#define KDIM  512

__device__ __forceinline__ float b2f(unsigned short u) {
  return __uint_as_float(((unsigned int)u) << 16);
}
__device__ __forceinline__ unsigned short f2bf(float f) {
  unsigned int u = __float_as_uint(f);
  u += 0x7FFFu + ((u >> 16) & 1u);   // round-to-nearest-even
  return (unsigned short)(u >> 16);
}
__device__ __forceinline__ float dev_load(const float* p) {
  return __hip_atomic_load(p, __ATOMIC_RELAXED, __HIP_MEMORY_SCOPE_AGENT);
}

typedef __attribute__((ext_vector_type(8))) short bf16x8;
typedef __attribute__((ext_vector_type(4))) float f32x4;

// ---------------------------------------------------------------------------
// prep: row inverse-norms for z1/z2 (rows 0..65535) and normalized bf16 weight
// ---------------------------------------------------------------------------
__global__ __launch_bounds__(256) void prep_kernel(
    const float* __restrict__ z1, const float* __restrict__ z2,
    const float* __restrict__ w, float* __restrict__ rnorm,
    unsigned short* __restrict__ wnb) {
  const int tid = threadIdx.x;
  const int wv = tid >> 6, ln = tid & 63;
  const int row = blockIdx.x * 4 + wv;   // 0..66047
  const float* src;
  if (row < NROWS)        src = z1 + (size_t)row * DDIM;
  else if (row < 2*NROWS) src = z2 + (size_t)(row - NROWS) * DDIM;
  else                    src = w  + (size_t)(row - 2*NROWS) * DDIM;
  float4 v0 = ((const float4*)src)[ln*2];
  float4 v1 = ((const float4*)src)[ln*2+1];
  float ss = v0.x*v0.x + v0.y*v0.y + v0.z*v0.z + v0.w*v0.w
           + v1.x*v1.x + v1.y*v1.y + v1.z*v1.z + v1.w*v1.w;
  #pragma unroll
  for (int off = 1; off < 64; off <<= 1) ss += __shfl_xor(ss, off);
  float rn = 1.0f / fmaxf(sqrtf(ss), 1e-12f);
  if (row < 2*NROWS) {
    if (ln == 0) rnorm[row] = rn;
  } else {
    int r = row - 2*NROWS;
    ushort4 o0 = make_ushort4(f2bf(v0.x*rn), f2bf(v0.y*rn), f2bf(v0.z*rn), f2bf(v0.w*rn));
    ushort4 o1 = make_ushort4(f2bf(v1.x*rn), f2bf(v1.y*rn), f2bf(v1.z*rn), f2bf(v1.w*rn));
    ushort4* dst = (ushort4*)(wnb + (size_t)r*DDIM + ln*8);
    dst[0] = o0; dst[1] = o1;
  }
}

// ---------------------------------------------------------------------------
// initvecs: zero the 20 column-sum buffers (T[20][2*512]) and the output
// ---------------------------------------------------------------------------
__global__ void initvecs_kernel(float* __restrict__ T, float* __restrict__ out) {
  int i = blockIdx.x * 256 + threadIdx.x;
  if (i < 20 * 1024) T[i] = 0.f;
  if (i == 0) out[0] = 0.f;
}

// ---------------------------------------------------------------------------
// gemm: zc[r,c] = sum_d (z[r,d]*rnorm[r]) * wnb[c,d]   (bf16 MFMA, A*B^T)
// 128x128 tile, BK=32, 4 waves each 64x64 via 4x4 of 16x16x32 MFMAs
// ---------------------------------------------------------------------------
__global__ __launch_bounds__(256) void gemm_kernel(
    const float* __restrict__ z1, const float* __restrict__ z2,
    const float* __restrict__ rnorm, const unsigned short* __restrict__ wnb,
    unsigned short* __restrict__ zc) {
  constexpr int LDT = 40;   // padded LDS stride (elements): 80B rows, 16B aligned
  __shared__ unsigned short As[128 * LDT];
  __shared__ unsigned short Bs[128 * LDT];
  const int tid = threadIdx.x;
  const int colBase = blockIdx.x * 128;
  const int rowBase = blockIdx.y * 128;
  const float* Aptr = (rowBase < NROWS) ? (z1 + (size_t)rowBase * DDIM)
                                        : (z2 + (size_t)(rowBase - NROWS) * DDIM);
  const int wv = tid >> 6, ln = tid & 63;
  const int wm = wv & 1, wn = wv >> 1;
  const int lrow = ln & 15, quad = ln >> 4;

  f32x4 acc[4][4] = {};

  for (int k0 = 0; k0 < DDIM; k0 += 32) {
    // stage A (fp32 -> normalized bf16): 128 rows x 32 k
    #pragma unroll
    for (int i = 0; i < 4; i++) {
      int idx = i * 256 + tid;            // 0..1023
      int r = idx >> 3;                   // 0..127
      int kk = (idx & 7) * 4;             // 0..28
      float4 v = *(const float4*)(Aptr + (size_t)r * DDIM + k0 + kk);
      float rn = rnorm[rowBase + r];
      ushort4 o = make_ushort4(f2bf(v.x*rn), f2bf(v.y*rn), f2bf(v.z*rn), f2bf(v.w*rn));
      *(ushort4*)(&As[r * LDT + kk]) = o;
    }
    // stage B (bf16 weight): 128 rows x 32 k
    #pragma unroll
    for (int i = 0; i < 2; i++) {
      int idx = i * 256 + tid;            // 0..511
      int r = idx >> 2;                   // 0..127
      int kk = (idx & 3) * 8;             // 0..24
      float4 v = *(const float4*)(wnb + (size_t)(colBase + r) * DDIM + k0 + kk);
      *(float4*)(&Bs[r * LDT + kk]) = v;
    }
    __syncthreads();
    bf16x8 af[4], bfr[4];
    #pragma unroll
    for (int mi = 0; mi < 4; mi++)
      af[mi] = *(const bf16x8*)(&As[(64*wm + 16*mi + lrow) * LDT + quad*8]);
    #pragma unroll
    for (int ni = 0; ni < 4; ni++)
      bfr[ni] = *(const bf16x8*)(&Bs[(64*wn + 16*ni + lrow) * LDT + quad*8]);
    #pragma unroll
    for (int mi = 0; mi < 4; mi++)
      #pragma unroll
      for (int ni = 0; ni < 4; ni++)
        acc[mi][ni] = __builtin_amdgcn_mfma_f32_16x16x32_bf16(
            af[mi], bfr[ni], acc[mi][ni], 0, 0, 0);
    __syncthreads();
  }
  // epilogue: C/D layout col=lane&15, row=(lane>>4)*4+reg
  #pragma unroll
  for (int mi = 0; mi < 4; mi++)
    #pragma unroll
    for (int ni = 0; ni < 4; ni++)
      #pragma unroll
      for (int r = 0; r < 4; r++) {
        size_t grow = (size_t)rowBase + 64*wm + 16*mi + quad*4 + r;
        int gcol = colBase + 64*wn + 16*ni + lrow;
        zc[grow * KDIM + gcol] = f2bf(acc[mi][ni][r]);
      }
}

// ---------------------------------------------------------------------------
// sink: fused 20-iteration sinkhorn + loss, single cooperative kernel.
// 256 blocks x 512 threads (8 waves). Each wave holds 16 rows of BOTH
// matrices in registers (16 x bf16x8 x 2 = 128 VGPRs); lane ln owns cols
// ln*8..ln*8+7. Per iteration: recompute e = exp(zc*20) (bit-identical to
// the old pass_kernel math), per-row butterfly for b, column sums -> LDS
// reduce -> atomicAdd into T[it], grid.sync(). Loss fused at the end
// (row pairing is lane-local since both matrices' rows live in the lane).
// ---------------------------------------------------------------------------
__global__ __launch_bounds__(512, 2) void sink_kernel(
    const unsigned short* __restrict__ zc,
    float* __restrict__ T, float* __restrict__ out) {
  cg::grid_group grid = cg::this_grid();
  __shared__ float red[8 * 1024];
  const int tid = threadIdx.x;
  const int wv = tid >> 6, ln = tid & 63;
  const int col0 = ln * 8;
  const size_t row0 = (size_t)blockIdx.x * 128 + (size_t)wv * 16;

  // load 16 rows of each matrix into registers (read zc exactly once)
  bf16x8 d1[16], d2[16];
  #pragma unroll
  for (int r = 0; r < 16; r++) {
    d1[r] = *(const bf16x8*)(zc + (row0 + r) * KDIM + col0);
    d2[r] = *(const bf16x8*)(zc + (row0 + r + (size_t)NROWS) * KDIM + col0);
  }

  #pragma unroll 1
  for (int it = 0; it < 20; it++) {
    float a1[8], a2[8];
    if (it > 0) {
      const float* Tp = T + (size_t)(it - 1) * 1024;
      #pragma unroll
      for (int j = 0; j < 8; j++) {
        a1[j] = 1.0f / (512.0f * dev_load(Tp + col0 + j));
        a2[j] = 1.0f / (512.0f * dev_load(Tp + 512 + col0 + j));
      }
    }
    float acc1[8] = {0,0,0,0,0,0,0,0};
    float acc2[8] = {0,0,0,0,0,0,0,0};
    #pragma unroll
    for (int r = 0; r < 16; r++) {
      float e[8];
      #pragma unroll
      for (int j = 0; j < 8; j++) e[j] = __expf(b2f((unsigned short)d1[r][j]) * 20.f);
      if (it > 0) {
        float part = e[0]*a1[0]+e[1]*a1[1]+e[2]*a1[2]+e[3]*a1[3]
                   + e[4]*a1[4]+e[5]*a1[5]+e[6]*a1[6]+e[7]*a1[7];
        #pragma unroll
        for (int off = 1; off < 64; off <<= 1) part += __shfl_xor(part, off);
        float bb = 1.0f / (32768.0f * part);
        #pragma unroll
        for (int j = 0; j < 8; j++) acc1[j] += e[j] * bb;
      } else {
        #pragma unroll
        for (int j = 0; j < 8; j++) acc1[j] += e[j];
      }
      #pragma unroll
      for (int j = 0; j < 8; j++) e[j] = __expf(b2f((unsigned short)d2[r][j]) * 20.f);
      if (it > 0) {
        float part = e[0]*a2[0]+e[1]*a2[1]+e[2]*a2[2]+e[3]*a2[3]
                   + e[4]*a2[4]+e[5]*a2[5]+e[6]*a2[6]+e[7]*a2[7];
        #pragma unroll
        for (int off = 1; off < 64; off <<= 1) part += __shfl_xor(part, off);
        float bb = 1.0f / (32768.0f * part);
        #pragma unroll
        for (int j = 0; j < 8; j++) acc2[j] += e[j] * bb;
      } else {
        #pragma unroll
        for (int j = 0; j < 8; j++) acc2[j] += e[j];
      }
    }
    // block reduce (8 waves) then one atomic per column per block
    #pragma unroll
    for (int j = 0; j < 8; j++) red[wv*1024 + col0 + j] = acc1[j];
    #pragma unroll
    for (int j = 0; j < 8; j++) red[wv*1024 + 512 + col0 + j] = acc2[j];
    __syncthreads();
    float s0 = 0.f, s1 = 0.f;
    #pragma unroll
    for (int w = 0; w < 8; w++) { s0 += red[w*1024 + tid]; s1 += red[w*1024 + 512 + tid]; }
    float* Tn = T + (size_t)it * 1024;
    unsafeAtomicAdd(&Tn[tid], s0);
    unsafeAtomicAdd(&Tn[512 + tid], s1);
    grid.sync();
  }

  // ---- fused loss using T19 ----
  {
    const float* Tl = T + (size_t)19 * 1024;
    float a1[8], a2[8];
    #pragma unroll
    for (int j = 0; j < 8; j++) {
      a1[j] = 1.0f / (512.0f * dev_load(Tl + col0 + j));
      a2[j] = 1.0f / (512.0f * dev_load(Tl + 512 + col0 + j));
    }
    const float invTau = 1.0f / 0.3f;
    float part = 0.f;
    #pragma unroll
    for (int r = 0; r < 16; r++) {
      float zf1[8], zf2[8];
      #pragma unroll
      for (int j = 0; j < 8; j++) {
        zf1[j] = b2f((unsigned short)d1[r][j]);
        zf2[j] = b2f((unsigned short)d2[r][j]);
      }
      float m1 = -1e30f, m2 = -1e30f;
      #pragma unroll
      for (int j = 0; j < 8; j++) { m1 = fmaxf(m1, zf1[j]); m2 = fmaxf(m2, zf2[j]); }
      #pragma unroll
      for (int off = 1; off < 64; off <<= 1) {
        m1 = fmaxf(m1, __shfl_xor(m1, off));
        m2 = fmaxf(m2, __shfl_xor(m2, off));
      }
      float se1 = 0.f, se2 = 0.f;
      #pragma unroll
      for (int j = 0; j < 8; j++) {
        se1 += __expf((zf1[j] - m1) * invTau);
        se2 += __expf((zf2[j] - m2) * invTau);
      }
      #pragma unroll
      for (int off = 1; off < 64; off <<= 1) {
        se1 += __shfl_xor(se1, off);
        se2 += __shfl_xor(se2, off);
      }
      float ls1 = m1 * invTau + __logf(se1);
      float ls2 = m2 * invTau + __logf(se2);
      float s1 = 0.f, n1 = 0.f, s2 = 0.f, n2 = 0.f;
      #pragma unroll
      for (int j = 0; j < 8; j++) {
        float e1 = __expf(zf1[j] * 20.f) * a1[j];
        s1 += e1; n1 += e1 * (zf2[j] * invTau - ls2);
        float e2 = __expf(zf2[j] * 20.f) * a2[j];
        s2 += e2; n2 += e2 * (zf1[j] * invTau - ls1);
      }
      #pragma unroll
      for (int off = 1; off < 64; off <<= 1) {
        s1 += __shfl_xor(s1, off); n1 += __shfl_xor(n1, off);
        s2 += __shfl_xor(s2, off); n2 += __shfl_xor(n2, off);
      }
      part += n1 / s1 + n2 / s2;
    }
    if (ln == 0) red[wv] = part;
    __syncthreads();
    if (tid == 0) {
      float s = 0.f;
      #pragma unroll
      for (int w = 0; w < 8; w++) s += red[w];
      unsafeAtomicAdd(out, -s * (1.0f / 32768.0f));
    }
  }
}

// ---------------------------------------------------------------------------
extern "C" void kernel_launch(void* const* d_in, const int* in_sizes, int n_in,
                              void* d_out, int out_size, void* d_ws, size_t ws_size,
                              hipStream_t stream) {
  (void)in_sizes; (void)n_in; (void)out_size; (void)ws_size;
  const float* z1 = (const float*)d_in[0];
  const float* z2 = (const float*)d_in[1];
  const float* w  = (const float*)d_in[2];
  float* out = (float*)d_out;
  char* ws = (char*)d_ws;
  // workspace layout
  unsigned short* zc    = (unsigned short*)ws;                         // 67,108,864 B
  float*          rnorm = (float*)(ws + (size_t)67108864);             //    262,144 B
  unsigned short* wnb   = (unsigned short*)(ws + (size_t)67371008);    //    524,288 B
  float*          T     = (float*)(ws + (size_t)67895296);             //     81,920 B

  hipLaunchKernelGGL(prep_kernel, dim3(16512), dim3(256), 0, stream, z1, z2, w, rnorm, wnb);
  hipLaunchKernelGGL(initvecs_kernel, dim3(80), dim3(256), 0, stream, T, out);
  hipLaunchKernelGGL(gemm_kernel, dim3(4, 512), dim3(256), 0, stream, z1, z2, rnorm, wnb, zc);
  {
    void* args[] = {(void*)&zc, (void*)&T, (void*)&out};
    hipLaunchCooperativeKernel((const void*)sink_kernel, dim3(256), dim3(512),
                               args, 0, stream);
  }
}